// Round 3
// baseline (182.109 us; speedup 1.0000x reference)
//
#include <hip/hip_runtime.h>
#include <climits>
#include <math.h>

// ---------------------------------------------------------------------------
// DescriptorModel: neutron-weighted G(r), T(r), S(Q), tetrahedral q over Si.
// R3 restructure:
//   k_init  (17 blocks): cell inverse + scalars (block 0, incl. Si/O list
//           compaction via prefix sum), hist zero + float4 pack (blocks 1-16).
//   k_hist  (tile-pair grid): symmetry-halved pair histogram. Upper-tri
//           128x128 tile pairs, off-diag weight x2. Lanes = i, j wave-uniform
//           (scalar 16B load per 64 pairs). LDS hist per block, 16 global copies.
//   k_top4  (wave per Si): d2-compare top-4 over compacted O list, register
//           top-4 + shfl_xor merge (no LDS, no syncthreads), q_i accumulate.
//   k_finalize: G/T/S(Q)/q_tet as before.
// ---------------------------------------------------------------------------

#define B_SI_F 4.1491f
#define B_O_F  5.803f
#define CUTOFF_F 3.5f
#define NCOPIES 16

// ws float layout:
//  [0..8]  inv(cell)   [9] w_scale   [10] rho   [11] diag flag
//  [12] sum(q_i*vf)    [13] sum(vf)  [14] n_si (int)  [15] n_o (int)
//  [16 .. 16+NCOPIES*nbins)  histogram copies
//  [WS_POS4 ..]  p4[N] float4 (x,y,z,b) ; then si4[N] ; then o4[N]
#define WS_HIST 16
#define WS_POS4 4096   // requires 16 + NCOPIES*nbins <= 4096

__device__ __forceinline__ bool dless(float da, int ia, float db, int ib) {
    return (da < db) || (da == db && ia < ib);
}

struct CellK {
    float ci0, ci1, ci2, ci3, ci4, ci5, ci6, ci7, ci8;
    float c0, c1, c2, c3, c4, c5, c6, c7, c8;
};

__device__ __forceinline__ CellK load_cell(const float* __restrict__ ws,
                                           const float* __restrict__ cellm) {
    CellK K;
    K.ci0 = ws[0]; K.ci1 = ws[1]; K.ci2 = ws[2];
    K.ci3 = ws[3]; K.ci4 = ws[4]; K.ci5 = ws[5];
    K.ci6 = ws[6]; K.ci7 = ws[7]; K.ci8 = ws[8];
    K.c0 = cellm[0]; K.c1 = cellm[1]; K.c2 = cellm[2];
    K.c3 = cellm[3]; K.c4 = cellm[4]; K.c5 = cellm[5];
    K.c6 = cellm[6]; K.c7 = cellm[7]; K.c8 = cellm[8];
    return K;
}

template<bool DIAG>
__device__ __forceinline__ void min_image(const CellK& K,
                                          float dx, float dy, float dz,
                                          float& ex, float& ey, float& ez) {
    if (DIAG) {
        float t0 = dx * K.ci0, t1 = dy * K.ci4, t2 = dz * K.ci8;
        t0 -= rintf(t0);  t1 -= rintf(t1);  t2 -= rintf(t2);
        ex = t0 * K.c0;  ey = t1 * K.c4;  ez = t2 * K.c8;
    } else {
        float f0 = dx*K.ci0 + dy*K.ci3 + dz*K.ci6;
        float f1 = dx*K.ci1 + dy*K.ci4 + dz*K.ci7;
        float f2 = dx*K.ci2 + dy*K.ci5 + dz*K.ci8;
        f0 -= rintf(f0);  f1 -= rintf(f1);  f2 -= rintf(f2);
        ex = f0*K.c0 + f1*K.c3 + f2*K.c6;
        ey = f0*K.c1 + f1*K.c4 + f2*K.c7;
        ez = f0*K.c2 + f1*K.c5 + f2*K.c8;
    }
}

// ---------------------------------------------------------------------------
// k_init: 17 blocks x 256. Block 0: compaction + scalars. Blocks 1-16: hist
// zero + p4 pack.
__global__ __launch_bounds__(256) void k_init(const float* __restrict__ cell,
                                              const float* __restrict__ pos,
                                              const int* __restrict__ species,
                                              float* __restrict__ ws, int N, int nbins) {
    const int tid = threadIdx.x;
    float4* p4  = (float4*)(ws + WS_POS4);
    float4* si4 = p4 + N;
    float4* o4  = si4 + N;

    if (blockIdx.x != 0) {
        const int nb = (int)gridDim.x - 1;      // 16
        const int cid = (int)blockIdx.x - 1;
        // zero hist copies (split across blocks 1..16)
        const int tot = NCOPIES * nbins;
        for (int i = cid * 256 + tid; i < tot; i += nb * 256)
            ws[WS_HIST + i] = 0.0f;
        // pack p4
        for (int j = cid * 256 + tid; j < N; j += nb * 256) {
            float b = (species[j] == 0) ? B_SI_F : B_O_F;
            p4[j] = make_float4(pos[3*j], pos[3*j+1], pos[3*j+2], b);
        }
        return;
    }

    // ---- block 0: ordered compaction of Si / O lists ----
    const int per = (N + 255) / 256;
    const int lo = tid * per, hi = min(N, lo + per);
    int csi = 0, co = 0;
    for (int j = lo; j < hi; ++j) {
        if (species[j] == 0) csi++; else co++;
    }
    __shared__ int psi[256], po[256];
    psi[tid] = csi; po[tid] = co;
    __syncthreads();
    for (int off = 1; off < 256; off <<= 1) {
        int a = (tid >= off) ? psi[tid - off] : 0;
        int b = (tid >= off) ? po[tid - off]  : 0;
        __syncthreads();
        psi[tid] += a; po[tid] += b;
        __syncthreads();
    }
    int wsi = psi[tid] - csi, wo = po[tid] - co;
    for (int j = lo; j < hi; ++j) {
        float x = pos[3*j], y = pos[3*j+1], z = pos[3*j+2];
        if (species[j] == 0) si4[wsi++] = make_float4(x, y, z, __int_as_float(j));
        else                 o4[wo++]   = make_float4(x, y, z, __int_as_float(j));
    }

    if (tid == 0) {
        int nSi = psi[255];
        ((int*)ws)[14] = nSi;
        ((int*)ws)[15] = po[255];
        double m[9];
        #pragma unroll
        for (int i = 0; i < 9; ++i) m[i] = (double)cell[i];
        double det = m[0]*(m[4]*m[8]-m[5]*m[7])
                   - m[1]*(m[3]*m[8]-m[5]*m[6])
                   + m[2]*(m[3]*m[7]-m[4]*m[6]);
        double inv[9];
        inv[0] =  (m[4]*m[8]-m[5]*m[7])/det;
        inv[1] = -(m[1]*m[8]-m[2]*m[7])/det;
        inv[2] =  (m[1]*m[5]-m[2]*m[4])/det;
        inv[3] = -(m[3]*m[8]-m[5]*m[6])/det;
        inv[4] =  (m[0]*m[8]-m[2]*m[6])/det;
        inv[5] = -(m[0]*m[5]-m[2]*m[3])/det;
        inv[6] =  (m[3]*m[7]-m[4]*m[6])/det;
        inv[7] = -(m[0]*m[7]-m[1]*m[6])/det;
        inv[8] =  (m[0]*m[4]-m[1]*m[3])/det;
        #pragma unroll
        for (int i = 0; i < 9; ++i) ws[i] = (float)inv[i];
        float mean_b = ((float)nSi * B_SI_F + (float)(N - nSi) * B_O_F) / (float)N;
        ws[9]  = 1.0f / (mean_b * mean_b);
        ws[10] = (float)N / (float)fabs(det);
        bool diag = (cell[1] == 0.0f) && (cell[2] == 0.0f) && (cell[3] == 0.0f) &&
                    (cell[5] == 0.0f) && (cell[6] == 0.0f) && (cell[7] == 0.0f);
        ws[11] = diag ? 1.0f : 0.0f;
        ws[12] = 0.0f;
        ws[13] = 0.0f;
    }
}

// ---------------------------------------------------------------------------
// k_hist: symmetry-halved pair histogram over 128x128 tile pairs.
template<bool DIAG>
__device__ __forceinline__ void hist_sweep(const CellK& K, const float4* __restrict__ p4,
                                           int jbase, int jend,
                                           float xi, float yi, float zi, float wi,
                                           float rb0, float inv_dr, int nbins_m1,
                                           float* shist) {
    #pragma unroll 4
    for (int j = jbase; j < jend; ++j) {
        int ju = __builtin_amdgcn_readfirstlane(j);   // wave-uniform -> s_load
        const float4 pj = p4[ju];
        float ex, ey, ez;
        min_image<DIAG>(K, xi - pj.x, yi - pj.y, zi - pj.z, ex, ey, ez);
        float dist = __builtin_amdgcn_sqrtf(fmaf(ex, ex, fmaf(ey, ey, ez * ez)));
        float x  = (dist - rb0) * inv_dr;
        float fl = floorf(x);
        int   i0 = (int)fl;
        if (i0 >= 0 && i0 < nbins_m1) {
            float w = wi * pj.w;
            float f = x - fl;
            atomicAdd(&shist[i0],     w * (1.0f - f));
            atomicAdd(&shist[i0 + 1], w * f);
        }
    }
}

__global__ __launch_bounds__(256) void k_hist(const float* __restrict__ cellm,
                                              const float* __restrict__ rbins,
                                              float* __restrict__ ws,
                                              int N, int nbins, int T) {
    const int tid = threadIdx.x;
    const int bid = blockIdx.x;
    const int jhalf = bid & 1;
    int rem = bid >> 1;
    int ti = 0;
    while (rem >= T - ti) { rem -= T - ti; ti++; }
    const int tj = ti + rem;

    __shared__ float shist[256];
    for (int t = tid; t < 256; t += 256) shist[t] = 0.0f;

    const CellK K = load_cell(ws, cellm);
    const float w_scale = ws[9];
    const bool  diag    = (ws[11] != 0.0f);
    const float rb0     = rbins[0];
    const float inv_dr  = 1.0f / (rbins[1] - rbins[0]);
    const int   nbins_m1 = nbins - 1;

    const float4* __restrict__ p4 = (const float4*)(ws + WS_POS4);
    const int il  = tid & 127;
    const int sub = tid >> 7;
    const int i   = ti * 128 + il;
    const float4 pi_ = p4[min(i, N - 1)];
    const float xi = pi_.x, yi = pi_.y, zi = pi_.z;
    const float wmul = (ti == tj) ? 1.0f : 2.0f;
    const float wi = (i < N) ? pi_.w * w_scale * wmul : 0.0f;

    const int jbase = tj * 128 + jhalf * 64 + sub * 32;
    const int jend  = min(jbase + 32, N);

    __syncthreads();

    if (diag) hist_sweep<true >(K, p4, jbase, jend, xi, yi, zi, wi, rb0, inv_dr, nbins_m1, shist);
    else      hist_sweep<false>(K, p4, jbase, jend, xi, yi, zi, wi, rb0, inv_dr, nbins_m1, shist);

    __syncthreads();

    float* gh = ws + WS_HIST + (size_t)(bid % NCOPIES) * nbins;
    for (int t = tid; t < nbins; t += 256) {
        float h = shist[t];
        if (h != 0.0f) atomicAdd(&gh[t], h);
    }
}

// ---------------------------------------------------------------------------
// k_top4: one wave (64 threads) per Si atom; sweep compacted O list on d2.
__device__ __forceinline__ float sel4f(const float a[4], int p) {
    float r = a[0];
    r = (p == 1) ? a[1] : r;
    r = (p == 2) ? a[2] : r;
    r = (p == 3) ? a[3] : r;
    return r;
}
__device__ __forceinline__ int sel4i(const int a[4], int p) {
    int r = a[0];
    r = (p == 1) ? a[1] : r;
    r = (p == 2) ? a[2] : r;
    r = (p == 3) ? a[3] : r;
    return r;
}

template<bool DIAG>
__device__ __forceinline__ void top4_sweep(const CellK& K, const float4* __restrict__ o4,
                                           int no, int lane,
                                           float xi, float yi, float zi,
                                           float d2a[4], int ja[4]) {
    for (int k = lane; k < no; k += 64) {
        const float4 o = o4[k];
        float ex, ey, ez;
        min_image<DIAG>(K, xi - o.x, yi - o.y, zi - o.z, ex, ey, ez);
        float d2 = fmaf(ex, ex, fmaf(ey, ey, ez * ez));
        int jo = __float_as_int(o.w);
        if (dless(d2, jo, d2a[3], ja[3])) {
            d2a[3] = d2; ja[3] = jo;
            #pragma unroll
            for (int q = 3; q > 0; --q) {
                if (dless(d2a[q], ja[q], d2a[q-1], ja[q-1])) {
                    float td = d2a[q]; d2a[q] = d2a[q-1]; d2a[q-1] = td;
                    int   tj = ja[q];  ja[q]  = ja[q-1];  ja[q-1]  = tj;
                }
            }
        }
    }
}

__global__ __launch_bounds__(64) void k_top4(const float* __restrict__ cellm,
                                             float* __restrict__ ws, int N) {
    const int nsi = ((const int*)ws)[14];
    const int s = blockIdx.x;
    if (s >= nsi) return;
    const int no = ((const int*)ws)[15];
    const int lane = threadIdx.x;

    const CellK K = load_cell(ws, cellm);
    const bool diag = (ws[11] != 0.0f);

    const float4* __restrict__ p4  = (const float4*)(ws + WS_POS4);
    const float4* __restrict__ si4 = p4 + N;
    const float4* __restrict__ o4  = si4 + N;

    const float4 sc = si4[s];
    const float xi = sc.x, yi = sc.y, zi = sc.z;

    float d2a[4] = {1e12f, 1e12f, 1e12f, 1e12f};
    int   ja[4]  = {INT_MAX, INT_MAX, INT_MAX, INT_MAX};

    if (diag) top4_sweep<true >(K, o4, no, lane, xi, yi, zi, d2a, ja);
    else      top4_sweep<false>(K, o4, no, lane, xi, yi, zi, d2a, ja);

    // wave-wide merge: 6 butterfly rounds
    for (int off = 1; off < 64; off <<= 1) {
        float bd[4]; int bj[4];
        #pragma unroll
        for (int k = 0; k < 4; ++k) {
            bd[k] = __shfl_xor(d2a[k], off, 64);
            bj[k] = __shfl_xor(ja[k],  off, 64);
        }
        float od[4]; int oj[4];
        int pa = 0, pb = 0;
        #pragma unroll
        for (int k = 0; k < 4; ++k) {
            float ad  = sel4f(d2a, pa); int ai = sel4i(ja, pa);
            float bdp = sel4f(bd,  pb); int bi = sel4i(bj, pb);
            bool ta = dless(ad, ai, bdp, bi);
            od[k] = ta ? ad : bdp;
            oj[k] = ta ? ai : bi;
            pa += ta ? 1 : 0;
            pb += ta ? 0 : 1;
        }
        #pragma unroll
        for (int k = 0; k < 4; ++k) { d2a[k] = od[k]; ja[k] = oj[k]; }
    }

    if (lane == 0) {
        float dd[4];
        #pragma unroll
        for (int k = 0; k < 4; ++k) dd[k] = sqrtf(d2a[k]);
        if (dd[3] < CUTOFF_F) {
            float ux[4], uy[4], uz[4];
            #pragma unroll
            for (int k = 0; k < 4; ++k) {
                const float4 pj = p4[ja[k]];
                float ex, ey, ez;
                if (diag) min_image<true >(K, xi - pj.x, yi - pj.y, zi - pj.z, ex, ey, ez);
                else      min_image<false>(K, xi - pj.x, yi - pj.y, zi - pj.z, ex, ey, ez);
                ux[k] = ex / dd[k];
                uy[k] = ey / dd[k];
                uz[k] = ez / dd[k];
            }
            float s2 = 0.0f;
            #pragma unroll
            for (int k = 0; k < 4; ++k)
                #pragma unroll
                for (int l = k + 1; l < 4; ++l) {
                    float cs = ux[k]*ux[l] + uy[k]*uy[l] + uz[k]*uz[l];
                    float t  = cs + (1.0f / 3.0f);
                    s2 += t * t;
                }
            float qi = 1.0f - 0.375f * s2;
            atomicAdd(&ws[12], qi);
            atomicAdd(&ws[13], 1.0f);
        }
    }
}

// ---------------------------------------------------------------------------
__global__ void k_finalize(const float* __restrict__ ws,
                           const float* __restrict__ rbins,
                           const float* __restrict__ qbins,
                           float* __restrict__ out,
                           int N, int nbins, int nq) {
    __shared__ float G[512];
    const int tid = threadIdx.x;
    const float rho = ws[10];
    const float dr  = rbins[1] - rbins[0];
    const float FOURPI = 4.0f * 3.14159265358979323846f;

    for (int t = tid; t < nbins; t += blockDim.x) {
        float h = 0.0f;
        for (int c = 0; c < NCOPIES; ++c) h += ws[WS_HIST + c * nbins + t];
        float r = rbins[t];
        float shell = FOURPI * r * r * dr;
        float g = h / ((float)N * rho * shell);
        G[t] = g;
        if (blockIdx.x == 0) {
            out[t] = g;
            out[nbins + t] = FOURPI * rho * r * g;
        }
    }
    __syncthreads();

    int q = blockIdx.x * blockDim.x + tid;
    if (q < nq) {
        float qq = qbins[q];
        float s = 0.0f;
        for (int t = 0; t < nbins; ++t) {
            float r  = rbins[t];
            float qr = qq * r;
            float sc = sinf(qr) / qr;          // jnp.sinc(qr/pi)
            s += r * r * (G[t] - 1.0f) * sc;
        }
        out[2 * nbins + q] = 1.0f + FOURPI * rho * dr * s;
    }
    if (blockIdx.x == 0 && tid == 0) {
        out[2 * nbins + nq] = ws[12] / fmaxf(ws[13], 1.0f);
    }
}

// ---------------------------------------------------------------------------
extern "C" void kernel_launch(void* const* d_in, const int* in_sizes, int n_in,
                              void* d_out, int out_size, void* d_ws, size_t ws_size,
                              hipStream_t stream) {
    const float* pos     = (const float*)d_in[0];
    const float* cell    = (const float*)d_in[1];
    const float* rbins   = (const float*)d_in[2];
    const float* qbins   = (const float*)d_in[3];
    const int*   species = (const int*)d_in[4];
    float* out = (float*)d_out;
    float* ws  = (float*)d_ws;

    const int N     = in_sizes[4];
    const int nbins = in_sizes[2];
    const int nq    = in_sizes[3];

    const int T = (N + 127) / 128;          // 128-atom tiles
    const int P = T * (T + 1) / 2;          // upper-tri tile pairs

    k_init<<<17, 256, 0, stream>>>(cell, pos, species, ws, N, nbins);
    k_hist<<<2 * P, 256, 0, stream>>>(cell, rbins, ws, N, nbins, T);
    k_top4<<<N, 64, 0, stream>>>(cell, ws, N);
    k_finalize<<<(nq + 255) / 256, 256, 0, stream>>>(ws, rbins, qbins, out, N, nbins, nq);
}

// Round 4
// 162.604 us; speedup vs baseline: 1.1200x; 1.1200x over previous
//
#include <hip/hip_runtime.h>
#include <climits>
#include <math.h>

// ---------------------------------------------------------------------------
// DescriptorModel: neutron-weighted G(r), T(r), S(Q), tetrahedral q over Si.
// R4: kill the same-address atomic serialization found in R3 (2730 fp32
// atomicAdds to ws[12]/ws[13] ~= 55us). k_top4 now writes per-Si (qi*vf, vf)
// to private slots; k_finalize block 0 tree-reduces them. No global atomics
// remain except the 16-copy histogram flush (3200 distinct addresses).
// ---------------------------------------------------------------------------

#define B_SI_F 4.1491f
#define B_O_F  5.803f
#define CUTOFF_F 3.5f
#define NCOPIES 16

// ws float layout:
//  [0..8]  inv(cell)   [9] w_scale   [10] rho   [11] diag flag
//  [14] n_si (int)  [15] n_o (int)
//  [16 .. 16+NCOPIES*nbins)  histogram copies
//  [WS_POS4 ..]  p4[N] float4 ; si4[N] ; o4[N] ; qv[2N] (per-Si qi*vf, vf)
#define WS_HIST 16
#define WS_POS4 4096   // requires 16 + NCOPIES*nbins <= 4096

__device__ __forceinline__ bool dless(float da, int ia, float db, int ib) {
    return (da < db) || (da == db && ia < ib);
}

struct CellK {
    float ci0, ci1, ci2, ci3, ci4, ci5, ci6, ci7, ci8;
    float c0, c1, c2, c3, c4, c5, c6, c7, c8;
};

__device__ __forceinline__ CellK load_cell(const float* __restrict__ ws,
                                           const float* __restrict__ cellm) {
    CellK K;
    K.ci0 = ws[0]; K.ci1 = ws[1]; K.ci2 = ws[2];
    K.ci3 = ws[3]; K.ci4 = ws[4]; K.ci5 = ws[5];
    K.ci6 = ws[6]; K.ci7 = ws[7]; K.ci8 = ws[8];
    K.c0 = cellm[0]; K.c1 = cellm[1]; K.c2 = cellm[2];
    K.c3 = cellm[3]; K.c4 = cellm[4]; K.c5 = cellm[5];
    K.c6 = cellm[6]; K.c7 = cellm[7]; K.c8 = cellm[8];
    return K;
}

template<bool DIAG>
__device__ __forceinline__ void min_image(const CellK& K,
                                          float dx, float dy, float dz,
                                          float& ex, float& ey, float& ez) {
    if (DIAG) {
        float t0 = dx * K.ci0, t1 = dy * K.ci4, t2 = dz * K.ci8;
        t0 -= rintf(t0);  t1 -= rintf(t1);  t2 -= rintf(t2);
        ex = t0 * K.c0;  ey = t1 * K.c4;  ez = t2 * K.c8;
    } else {
        float f0 = dx*K.ci0 + dy*K.ci3 + dz*K.ci6;
        float f1 = dx*K.ci1 + dy*K.ci4 + dz*K.ci7;
        float f2 = dx*K.ci2 + dy*K.ci5 + dz*K.ci8;
        f0 -= rintf(f0);  f1 -= rintf(f1);  f2 -= rintf(f2);
        ex = f0*K.c0 + f1*K.c3 + f2*K.c6;
        ey = f0*K.c1 + f1*K.c4 + f2*K.c7;
        ez = f0*K.c2 + f1*K.c5 + f2*K.c8;
    }
}

// ---------------------------------------------------------------------------
__global__ __launch_bounds__(256) void k_init(const float* __restrict__ cell,
                                              const float* __restrict__ pos,
                                              const int* __restrict__ species,
                                              float* __restrict__ ws, int N, int nbins) {
    const int tid = threadIdx.x;
    float4* p4  = (float4*)(ws + WS_POS4);
    float4* si4 = p4 + N;
    float4* o4  = si4 + N;

    if (blockIdx.x != 0) {
        const int nb = (int)gridDim.x - 1;      // 16
        const int cid = (int)blockIdx.x - 1;
        const int tot = NCOPIES * nbins;
        for (int i = cid * 256 + tid; i < tot; i += nb * 256)
            ws[WS_HIST + i] = 0.0f;
        for (int j = cid * 256 + tid; j < N; j += nb * 256) {
            float b = (species[j] == 0) ? B_SI_F : B_O_F;
            p4[j] = make_float4(pos[3*j], pos[3*j+1], pos[3*j+2], b);
        }
        return;
    }

    // ---- block 0: ordered compaction of Si / O lists ----
    const int per = (N + 255) / 256;
    const int lo = tid * per, hi = min(N, lo + per);
    int csi = 0, co = 0;
    for (int j = lo; j < hi; ++j) {
        if (species[j] == 0) csi++; else co++;
    }
    __shared__ int psi[256], po[256];
    psi[tid] = csi; po[tid] = co;
    __syncthreads();
    for (int off = 1; off < 256; off <<= 1) {
        int a = (tid >= off) ? psi[tid - off] : 0;
        int b = (tid >= off) ? po[tid - off]  : 0;
        __syncthreads();
        psi[tid] += a; po[tid] += b;
        __syncthreads();
    }
    int wsi = psi[tid] - csi, wo = po[tid] - co;
    for (int j = lo; j < hi; ++j) {
        float x = pos[3*j], y = pos[3*j+1], z = pos[3*j+2];
        if (species[j] == 0) si4[wsi++] = make_float4(x, y, z, __int_as_float(j));
        else                 o4[wo++]   = make_float4(x, y, z, __int_as_float(j));
    }

    if (tid == 0) {
        int nSi = psi[255];
        ((int*)ws)[14] = nSi;
        ((int*)ws)[15] = po[255];
        double m[9];
        #pragma unroll
        for (int i = 0; i < 9; ++i) m[i] = (double)cell[i];
        double det = m[0]*(m[4]*m[8]-m[5]*m[7])
                   - m[1]*(m[3]*m[8]-m[5]*m[6])
                   + m[2]*(m[3]*m[7]-m[4]*m[6]);
        double inv[9];
        inv[0] =  (m[4]*m[8]-m[5]*m[7])/det;
        inv[1] = -(m[1]*m[8]-m[2]*m[7])/det;
        inv[2] =  (m[1]*m[5]-m[2]*m[4])/det;
        inv[3] = -(m[3]*m[8]-m[5]*m[6])/det;
        inv[4] =  (m[0]*m[8]-m[2]*m[6])/det;
        inv[5] = -(m[0]*m[5]-m[2]*m[3])/det;
        inv[6] =  (m[3]*m[7]-m[4]*m[6])/det;
        inv[7] = -(m[0]*m[7]-m[1]*m[6])/det;
        inv[8] =  (m[0]*m[4]-m[1]*m[3])/det;
        #pragma unroll
        for (int i = 0; i < 9; ++i) ws[i] = (float)inv[i];
        float mean_b = ((float)nSi * B_SI_F + (float)(N - nSi) * B_O_F) / (float)N;
        ws[9]  = 1.0f / (mean_b * mean_b);
        ws[10] = (float)N / (float)fabs(det);
        bool diag = (cell[1] == 0.0f) && (cell[2] == 0.0f) && (cell[3] == 0.0f) &&
                    (cell[5] == 0.0f) && (cell[6] == 0.0f) && (cell[7] == 0.0f);
        ws[11] = diag ? 1.0f : 0.0f;
    }
}

// ---------------------------------------------------------------------------
// k_hist: symmetry-halved pair histogram over 128x128 tile pairs.
template<bool DIAG>
__device__ __forceinline__ void hist_sweep(const CellK& K, const float4* __restrict__ p4,
                                           int jbase, int jend,
                                           float xi, float yi, float zi, float wi,
                                           float rb0, float inv_dr, int nbins_m1,
                                           float* shist) {
    #pragma unroll 4
    for (int j = jbase; j < jend; ++j) {
        int ju = __builtin_amdgcn_readfirstlane(j);   // wave-uniform -> s_load
        const float4 pj = p4[ju];
        float ex, ey, ez;
        min_image<DIAG>(K, xi - pj.x, yi - pj.y, zi - pj.z, ex, ey, ez);
        float dist = __builtin_amdgcn_sqrtf(fmaf(ex, ex, fmaf(ey, ey, ez * ez)));
        float x  = (dist - rb0) * inv_dr;
        float fl = floorf(x);
        int   i0 = (int)fl;
        if (i0 >= 0 && i0 < nbins_m1) {
            float w = wi * pj.w;
            float f = x - fl;
            atomicAdd(&shist[i0],     w * (1.0f - f));
            atomicAdd(&shist[i0 + 1], w * f);
        }
    }
}

__global__ __launch_bounds__(256) void k_hist(const float* __restrict__ cellm,
                                              const float* __restrict__ rbins,
                                              float* __restrict__ ws,
                                              int N, int nbins, int T) {
    const int tid = threadIdx.x;
    const int bid = blockIdx.x;
    const int jhalf = bid & 1;
    int rem = bid >> 1;
    int ti = 0;
    while (rem >= T - ti) { rem -= T - ti; ti++; }
    const int tj = ti + rem;

    __shared__ float shist[256];
    for (int t = tid; t < 256; t += 256) shist[t] = 0.0f;

    const CellK K = load_cell(ws, cellm);
    const float w_scale = ws[9];
    const bool  diag    = (ws[11] != 0.0f);
    const float rb0     = rbins[0];
    const float inv_dr  = 1.0f / (rbins[1] - rbins[0]);
    const int   nbins_m1 = nbins - 1;

    const float4* __restrict__ p4 = (const float4*)(ws + WS_POS4);
    const int il  = tid & 127;
    const int sub = tid >> 7;
    const int i   = ti * 128 + il;
    const float4 pi_ = p4[min(i, N - 1)];
    const float xi = pi_.x, yi = pi_.y, zi = pi_.z;
    const float wmul = (ti == tj) ? 1.0f : 2.0f;
    const float wi = (i < N) ? pi_.w * w_scale * wmul : 0.0f;

    const int jbase = tj * 128 + jhalf * 64 + sub * 32;
    const int jend  = min(jbase + 32, N);

    __syncthreads();

    if (diag) hist_sweep<true >(K, p4, jbase, jend, xi, yi, zi, wi, rb0, inv_dr, nbins_m1, shist);
    else      hist_sweep<false>(K, p4, jbase, jend, xi, yi, zi, wi, rb0, inv_dr, nbins_m1, shist);

    __syncthreads();

    float* gh = ws + WS_HIST + (size_t)(bid % NCOPIES) * nbins;
    for (int t = tid; t < nbins; t += 256) {
        float h = shist[t];
        if (h != 0.0f) atomicAdd(&gh[t], h);
    }
}

// ---------------------------------------------------------------------------
// k_top4: one wave per Si atom; d2 top-4 over compacted O list; result to
// a private per-Si slot (NO global atomics).
__device__ __forceinline__ float sel4f(const float a[4], int p) {
    float r = a[0];
    r = (p == 1) ? a[1] : r;
    r = (p == 2) ? a[2] : r;
    r = (p == 3) ? a[3] : r;
    return r;
}
__device__ __forceinline__ int sel4i(const int a[4], int p) {
    int r = a[0];
    r = (p == 1) ? a[1] : r;
    r = (p == 2) ? a[2] : r;
    r = (p == 3) ? a[3] : r;
    return r;
}

template<bool DIAG>
__device__ __forceinline__ void top4_sweep(const CellK& K, const float4* __restrict__ o4,
                                           int no, int lane,
                                           float xi, float yi, float zi,
                                           float d2a[4], int ja[4]) {
    for (int k = lane; k < no; k += 64) {
        const float4 o = o4[k];
        float ex, ey, ez;
        min_image<DIAG>(K, xi - o.x, yi - o.y, zi - o.z, ex, ey, ez);
        float d2 = fmaf(ex, ex, fmaf(ey, ey, ez * ez));
        int jo = __float_as_int(o.w);
        if (dless(d2, jo, d2a[3], ja[3])) {
            d2a[3] = d2; ja[3] = jo;
            #pragma unroll
            for (int q = 3; q > 0; --q) {
                if (dless(d2a[q], ja[q], d2a[q-1], ja[q-1])) {
                    float td = d2a[q]; d2a[q] = d2a[q-1]; d2a[q-1] = td;
                    int   tj = ja[q];  ja[q]  = ja[q-1];  ja[q-1]  = tj;
                }
            }
        }
    }
}

__global__ __launch_bounds__(64) void k_top4(const float* __restrict__ cellm,
                                             float* __restrict__ ws, int N) {
    const int nsi = ((const int*)ws)[14];
    const int s = blockIdx.x;
    if (s >= nsi) return;
    const int no = ((const int*)ws)[15];
    const int lane = threadIdx.x;

    const CellK K = load_cell(ws, cellm);
    const bool diag = (ws[11] != 0.0f);

    const float4* __restrict__ p4  = (const float4*)(ws + WS_POS4);
    const float4* __restrict__ si4 = p4 + N;
    const float4* __restrict__ o4  = si4 + N;
    float* __restrict__ qv = ws + WS_POS4 + 12 * (size_t)N;   // [2N]

    const float4 sc = si4[s];
    const float xi = sc.x, yi = sc.y, zi = sc.z;

    float d2a[4] = {1e12f, 1e12f, 1e12f, 1e12f};
    int   ja[4]  = {INT_MAX, INT_MAX, INT_MAX, INT_MAX};

    if (diag) top4_sweep<true >(K, o4, no, lane, xi, yi, zi, d2a, ja);
    else      top4_sweep<false>(K, o4, no, lane, xi, yi, zi, d2a, ja);

    // wave-wide merge: 6 butterfly rounds
    for (int off = 1; off < 64; off <<= 1) {
        float bd[4]; int bj[4];
        #pragma unroll
        for (int k = 0; k < 4; ++k) {
            bd[k] = __shfl_xor(d2a[k], off, 64);
            bj[k] = __shfl_xor(ja[k],  off, 64);
        }
        float od[4]; int oj[4];
        int pa = 0, pb = 0;
        #pragma unroll
        for (int k = 0; k < 4; ++k) {
            float ad  = sel4f(d2a, pa); int ai = sel4i(ja, pa);
            float bdp = sel4f(bd,  pb); int bi = sel4i(bj, pb);
            bool ta = dless(ad, ai, bdp, bi);
            od[k] = ta ? ad : bdp;
            oj[k] = ta ? ai : bi;
            pa += ta ? 1 : 0;
            pb += ta ? 0 : 1;
        }
        #pragma unroll
        for (int k = 0; k < 4; ++k) { d2a[k] = od[k]; ja[k] = oj[k]; }
    }

    if (lane == 0) {
        float qiv = 0.0f, vf = 0.0f;
        float dd[4];
        #pragma unroll
        for (int k = 0; k < 4; ++k) dd[k] = sqrtf(d2a[k]);
        if (dd[3] < CUTOFF_F) {
            float ux[4], uy[4], uz[4];
            #pragma unroll
            for (int k = 0; k < 4; ++k) {
                const float4 pj = p4[ja[k]];
                float ex, ey, ez;
                if (diag) min_image<true >(K, xi - pj.x, yi - pj.y, zi - pj.z, ex, ey, ez);
                else      min_image<false>(K, xi - pj.x, yi - pj.y, zi - pj.z, ex, ey, ez);
                ux[k] = ex / dd[k];
                uy[k] = ey / dd[k];
                uz[k] = ez / dd[k];
            }
            float s2 = 0.0f;
            #pragma unroll
            for (int k = 0; k < 4; ++k)
                #pragma unroll
                for (int l = k + 1; l < 4; ++l) {
                    float cs = ux[k]*ux[l] + uy[k]*uy[l] + uz[k]*uz[l];
                    float t  = cs + (1.0f / 3.0f);
                    s2 += t * t;
                }
            qiv = 1.0f - 0.375f * s2;
            vf  = 1.0f;
        }
        qv[2*s]     = qiv;   // plain stores, zero contention
        qv[2*s + 1] = vf;
    }
}

// ---------------------------------------------------------------------------
__global__ __launch_bounds__(256) void k_finalize(const float* __restrict__ ws,
                                                  const float* __restrict__ rbins,
                                                  const float* __restrict__ qbins,
                                                  float* __restrict__ out,
                                                  int N, int nbins, int nq) {
    __shared__ float G[512];
    __shared__ float rq[256], rv[256];
    const int tid = threadIdx.x;
    const float rho = ws[10];
    const float dr  = rbins[1] - rbins[0];
    const float FOURPI = 4.0f * 3.14159265358979323846f;

    for (int t = tid; t < nbins; t += blockDim.x) {
        float h = 0.0f;
        for (int c = 0; c < NCOPIES; ++c) h += ws[WS_HIST + c * nbins + t];
        float r = rbins[t];
        float shell = FOURPI * r * r * dr;
        float g = h / ((float)N * rho * shell);
        G[t] = g;
        if (blockIdx.x == 0) {
            out[t] = g;
            out[nbins + t] = FOURPI * rho * r * g;
        }
    }

    // block 0: reduce per-Si (qi*vf, vf) slots
    if (blockIdx.x == 0) {
        const int nsi = ((const int*)ws)[14];
        const float* qv = ws + WS_POS4 + 12 * (size_t)N;
        float sq = 0.0f, sv = 0.0f;
        for (int s = tid; s < nsi; s += 256) {
            sq += qv[2*s];
            sv += qv[2*s + 1];
        }
        rq[tid] = sq; rv[tid] = sv;
    }
    __syncthreads();
    if (blockIdx.x == 0) {
        for (int s = 128; s > 0; s >>= 1) {
            if (tid < s) { rq[tid] += rq[tid + s]; rv[tid] += rv[tid + s]; }
            __syncthreads();
        }
        if (tid == 0)
            out[2 * nbins + nq] = rq[0] / fmaxf(rv[0], 1.0f);
    }

    int q = blockIdx.x * blockDim.x + tid;
    if (q < nq) {
        float qq = qbins[q];
        float s = 0.0f;
        for (int t = 0; t < nbins; ++t) {
            float r  = rbins[t];
            float qr = qq * r;
            float sc = sinf(qr) / qr;          // jnp.sinc(qr/pi)
            s += r * r * (G[t] - 1.0f) * sc;
        }
        out[2 * nbins + q] = 1.0f + FOURPI * rho * dr * s;
    }
}

// ---------------------------------------------------------------------------
extern "C" void kernel_launch(void* const* d_in, const int* in_sizes, int n_in,
                              void* d_out, int out_size, void* d_ws, size_t ws_size,
                              hipStream_t stream) {
    const float* pos     = (const float*)d_in[0];
    const float* cell    = (const float*)d_in[1];
    const float* rbins   = (const float*)d_in[2];
    const float* qbins   = (const float*)d_in[3];
    const int*   species = (const int*)d_in[4];
    float* out = (float*)d_out;
    float* ws  = (float*)d_ws;

    const int N     = in_sizes[4];
    const int nbins = in_sizes[2];
    const int nq    = in_sizes[3];

    const int T = (N + 127) / 128;          // 128-atom tiles
    const int P = T * (T + 1) / 2;          // upper-tri tile pairs

    k_init<<<17, 256, 0, stream>>>(cell, pos, species, ws, N, nbins);
    k_hist<<<2 * P, 256, 0, stream>>>(cell, rbins, ws, N, nbins, T);
    k_top4<<<N, 64, 0, stream>>>(cell, ws, N);
    k_finalize<<<(nq + 255) / 256, 256, 0, stream>>>(ws, rbins, qbins, out, N, nbins, nq);
}

// Round 5
// 152.781 us; speedup vs baseline: 1.1920x; 1.0643x over previous
//
#include <hip/hip_runtime.h>
#include <climits>
#include <math.h>

// ---------------------------------------------------------------------------
// DescriptorModel: neutron-weighted G(r), T(r), S(Q), tetrahedral q over Si.
// R5: k_top4 rewritten with NAMED-SCALAR top-4 state (no local arrays at all).
// R4 evidence: k_top4 51us with VALU 11%/occ 10%/HBM 0.1% and VGPR_Count=16
// -> local arrays (d2a[4]/ja[4]) were scratch-spilled; every insertion-sort
// access was a ~300-cyc private-memory op in a serial chain. Scalars + cndmask
// shift network + 4x extract-min shfl merge keep everything in VGPRs.
// ---------------------------------------------------------------------------

#define B_SI_F 4.1491f
#define B_O_F  5.803f
#define CUTOFF_F 3.5f
#define NCOPIES 16

// ws float layout:
//  [0..8]  inv(cell)   [9] w_scale   [10] rho   [11] diag flag
//  [14] n_si (int)  [15] n_o (int)
//  [16 .. 16+NCOPIES*nbins)  histogram copies
//  [WS_POS4 ..]  p4[N] float4 ; si4[N] ; o4[N] ; qv[2N] (per-Si qi*vf, vf)
#define WS_HIST 16
#define WS_POS4 4096   // requires 16 + NCOPIES*nbins <= 4096

__device__ __forceinline__ bool dless(float da, int ia, float db, int ib) {
    return (da < db) || (da == db && ia < ib);
}

struct CellK {
    float ci0, ci1, ci2, ci3, ci4, ci5, ci6, ci7, ci8;
    float c0, c1, c2, c3, c4, c5, c6, c7, c8;
};

__device__ __forceinline__ CellK load_cell(const float* __restrict__ ws,
                                           const float* __restrict__ cellm) {
    CellK K;
    K.ci0 = ws[0]; K.ci1 = ws[1]; K.ci2 = ws[2];
    K.ci3 = ws[3]; K.ci4 = ws[4]; K.ci5 = ws[5];
    K.ci6 = ws[6]; K.ci7 = ws[7]; K.ci8 = ws[8];
    K.c0 = cellm[0]; K.c1 = cellm[1]; K.c2 = cellm[2];
    K.c3 = cellm[3]; K.c4 = cellm[4]; K.c5 = cellm[5];
    K.c6 = cellm[6]; K.c7 = cellm[7]; K.c8 = cellm[8];
    return K;
}

template<bool DIAG>
__device__ __forceinline__ void min_image(const CellK& K,
                                          float dx, float dy, float dz,
                                          float& ex, float& ey, float& ez) {
    if (DIAG) {
        float t0 = dx * K.ci0, t1 = dy * K.ci4, t2 = dz * K.ci8;
        t0 -= rintf(t0);  t1 -= rintf(t1);  t2 -= rintf(t2);
        ex = t0 * K.c0;  ey = t1 * K.c4;  ez = t2 * K.c8;
    } else {
        float f0 = dx*K.ci0 + dy*K.ci3 + dz*K.ci6;
        float f1 = dx*K.ci1 + dy*K.ci4 + dz*K.ci7;
        float f2 = dx*K.ci2 + dy*K.ci5 + dz*K.ci8;
        f0 -= rintf(f0);  f1 -= rintf(f1);  f2 -= rintf(f2);
        ex = f0*K.c0 + f1*K.c3 + f2*K.c6;
        ey = f0*K.c1 + f1*K.c4 + f2*K.c7;
        ez = f0*K.c2 + f1*K.c5 + f2*K.c8;
    }
}

// ---------------------------------------------------------------------------
__global__ __launch_bounds__(256) void k_init(const float* __restrict__ cell,
                                              const float* __restrict__ pos,
                                              const int* __restrict__ species,
                                              float* __restrict__ ws, int N, int nbins) {
    const int tid = threadIdx.x;
    float4* p4  = (float4*)(ws + WS_POS4);
    float4* si4 = p4 + N;
    float4* o4  = si4 + N;

    if (blockIdx.x != 0) {
        const int nb = (int)gridDim.x - 1;      // 16
        const int cid = (int)blockIdx.x - 1;
        const int tot = NCOPIES * nbins;
        for (int i = cid * 256 + tid; i < tot; i += nb * 256)
            ws[WS_HIST + i] = 0.0f;
        for (int j = cid * 256 + tid; j < N; j += nb * 256) {
            float b = (species[j] == 0) ? B_SI_F : B_O_F;
            p4[j] = make_float4(pos[3*j], pos[3*j+1], pos[3*j+2], b);
        }
        return;
    }

    // ---- block 0: ordered compaction of Si / O lists ----
    const int per = (N + 255) / 256;
    const int lo = tid * per, hi = min(N, lo + per);
    int csi = 0, co = 0;
    for (int j = lo; j < hi; ++j) {
        if (species[j] == 0) csi++; else co++;
    }
    __shared__ int psi[256], po[256];
    psi[tid] = csi; po[tid] = co;
    __syncthreads();
    for (int off = 1; off < 256; off <<= 1) {
        int a = (tid >= off) ? psi[tid - off] : 0;
        int b = (tid >= off) ? po[tid - off]  : 0;
        __syncthreads();
        psi[tid] += a; po[tid] += b;
        __syncthreads();
    }
    int wsi = psi[tid] - csi, wo = po[tid] - co;
    for (int j = lo; j < hi; ++j) {
        float x = pos[3*j], y = pos[3*j+1], z = pos[3*j+2];
        if (species[j] == 0) si4[wsi++] = make_float4(x, y, z, __int_as_float(j));
        else                 o4[wo++]   = make_float4(x, y, z, __int_as_float(j));
    }

    if (tid == 0) {
        int nSi = psi[255];
        ((int*)ws)[14] = nSi;
        ((int*)ws)[15] = po[255];
        double m[9];
        #pragma unroll
        for (int i = 0; i < 9; ++i) m[i] = (double)cell[i];
        double det = m[0]*(m[4]*m[8]-m[5]*m[7])
                   - m[1]*(m[3]*m[8]-m[5]*m[6])
                   + m[2]*(m[3]*m[7]-m[4]*m[6]);
        double inv[9];
        inv[0] =  (m[4]*m[8]-m[5]*m[7])/det;
        inv[1] = -(m[1]*m[8]-m[2]*m[7])/det;
        inv[2] =  (m[1]*m[5]-m[2]*m[4])/det;
        inv[3] = -(m[3]*m[8]-m[5]*m[6])/det;
        inv[4] =  (m[0]*m[8]-m[2]*m[6])/det;
        inv[5] = -(m[0]*m[5]-m[2]*m[3])/det;
        inv[6] =  (m[3]*m[7]-m[4]*m[6])/det;
        inv[7] = -(m[0]*m[7]-m[1]*m[6])/det;
        inv[8] =  (m[0]*m[4]-m[1]*m[3])/det;
        #pragma unroll
        for (int i = 0; i < 9; ++i) ws[i] = (float)inv[i];
        float mean_b = ((float)nSi * B_SI_F + (float)(N - nSi) * B_O_F) / (float)N;
        ws[9]  = 1.0f / (mean_b * mean_b);
        ws[10] = (float)N / (float)fabs(det);
        bool diag = (cell[1] == 0.0f) && (cell[2] == 0.0f) && (cell[3] == 0.0f) &&
                    (cell[5] == 0.0f) && (cell[6] == 0.0f) && (cell[7] == 0.0f);
        ws[11] = diag ? 1.0f : 0.0f;
    }
}

// ---------------------------------------------------------------------------
// k_hist: symmetry-halved pair histogram over 128x128 tile pairs.
template<bool DIAG>
__device__ __forceinline__ void hist_sweep(const CellK& K, const float4* __restrict__ p4,
                                           int jbase, int jend,
                                           float xi, float yi, float zi, float wi,
                                           float rb0, float inv_dr, int nbins_m1,
                                           float* shist) {
    #pragma unroll 4
    for (int j = jbase; j < jend; ++j) {
        int ju = __builtin_amdgcn_readfirstlane(j);   // wave-uniform -> s_load
        const float4 pj = p4[ju];
        float ex, ey, ez;
        min_image<DIAG>(K, xi - pj.x, yi - pj.y, zi - pj.z, ex, ey, ez);
        float dist = __builtin_amdgcn_sqrtf(fmaf(ex, ex, fmaf(ey, ey, ez * ez)));
        float x  = (dist - rb0) * inv_dr;
        float fl = floorf(x);
        int   i0 = (int)fl;
        if (i0 >= 0 && i0 < nbins_m1) {
            float w = wi * pj.w;
            float f = x - fl;
            atomicAdd(&shist[i0],     w * (1.0f - f));
            atomicAdd(&shist[i0 + 1], w * f);
        }
    }
}

__global__ __launch_bounds__(256) void k_hist(const float* __restrict__ cellm,
                                              const float* __restrict__ rbins,
                                              float* __restrict__ ws,
                                              int N, int nbins, int T) {
    const int tid = threadIdx.x;
    const int bid = blockIdx.x;
    const int jhalf = bid & 1;
    int rem = bid >> 1;
    int ti = 0;
    while (rem >= T - ti) { rem -= T - ti; ti++; }
    const int tj = ti + rem;

    __shared__ float shist[256];
    for (int t = tid; t < 256; t += 256) shist[t] = 0.0f;

    const CellK K = load_cell(ws, cellm);
    const float w_scale = ws[9];
    const bool  diag    = (ws[11] != 0.0f);
    const float rb0     = rbins[0];
    const float inv_dr  = 1.0f / (rbins[1] - rbins[0]);
    const int   nbins_m1 = nbins - 1;

    const float4* __restrict__ p4 = (const float4*)(ws + WS_POS4);
    const int il  = tid & 127;
    const int sub = tid >> 7;
    const int i   = ti * 128 + il;
    const float4 pi_ = p4[min(i, N - 1)];
    const float xi = pi_.x, yi = pi_.y, zi = pi_.z;
    const float wmul = (ti == tj) ? 1.0f : 2.0f;
    const float wi = (i < N) ? pi_.w * w_scale * wmul : 0.0f;

    const int jbase = tj * 128 + jhalf * 64 + sub * 32;
    const int jend  = min(jbase + 32, N);

    __syncthreads();

    if (diag) hist_sweep<true >(K, p4, jbase, jend, xi, yi, zi, wi, rb0, inv_dr, nbins_m1, shist);
    else      hist_sweep<false>(K, p4, jbase, jend, xi, yi, zi, wi, rb0, inv_dr, nbins_m1, shist);

    __syncthreads();

    float* gh = ws + WS_HIST + (size_t)(bid % NCOPIES) * nbins;
    for (int t = tid; t < nbins; t += 256) {
        float h = shist[t];
        if (h != 0.0f) atomicAdd(&gh[t], h);
    }
}

// ---------------------------------------------------------------------------
// k_top4: one wave per Si atom; named-scalar top-4, nothing spillable.
template<bool DIAG>
__device__ __forceinline__ void top4_sweep_s(const CellK& K, const float4* __restrict__ o4,
                                             int no, int lane,
                                             float xi, float yi, float zi,
                                             float& e0, float& e1, float& e2, float& e3,
                                             int& j0, int& j1, int& j2, int& j3) {
    for (int k = lane; k < no; k += 64) {
        const float4 o = o4[k];
        float ex, ey, ez;
        min_image<DIAG>(K, xi - o.x, yi - o.y, zi - o.z, ex, ey, ez);
        float c  = fmaf(ex, ex, fmaf(ey, ey, ez * ez));
        int   jc = __float_as_int(o.w);
        if (dless(c, jc, e3, j3)) {            // rare; exec-mask skip otherwise
            bool lt2 = dless(c, jc, e2, j2);
            bool lt1 = dless(c, jc, e1, j1);
            bool lt0 = dless(c, jc, e0, j0);
            e3 = lt2 ? e2 : c;               j3 = lt2 ? j2 : jc;
            e2 = lt2 ? (lt1 ? e1 : c) : e2;  j2 = lt2 ? (lt1 ? j1 : jc) : j2;
            e1 = lt1 ? (lt0 ? e0 : c) : e1;  j1 = lt1 ? (lt0 ? j0 : jc) : j1;
            e0 = lt0 ? c : e0;               j0 = lt0 ? jc : j0;
        }
    }
}

__global__ __launch_bounds__(64) void k_top4(const float* __restrict__ cellm,
                                             float* __restrict__ ws, int N) {
    const int nsi = ((const int*)ws)[14];
    const int s = blockIdx.x;
    if (s >= nsi) return;
    const int no = ((const int*)ws)[15];
    const int lane = threadIdx.x;

    const CellK K = load_cell(ws, cellm);
    const bool diag = (ws[11] != 0.0f);

    const float4* __restrict__ p4  = (const float4*)(ws + WS_POS4);
    const float4* __restrict__ si4 = p4 + N;
    const float4* __restrict__ o4  = si4 + N;
    float* __restrict__ qv = ws + WS_POS4 + 12 * (size_t)N;   // [2N]

    const float4 sc = si4[s];
    const float xi = sc.x, yi = sc.y, zi = sc.z;

    float e0 = 1e12f, e1 = 1e12f, e2 = 1e12f, e3 = 1e12f;
    int   j0 = INT_MAX, j1 = INT_MAX, j2 = INT_MAX, j3 = INT_MAX;

    if (diag) top4_sweep_s<true >(K, o4, no, lane, xi, yi, zi, e0, e1, e2, e3, j0, j1, j2, j3);
    else      top4_sweep_s<false>(K, o4, no, lane, xi, yi, zi, e0, e1, e2, e3, j0, j1, j2, j3);

    // wave merge: extract global min 4x (scalar state only).
    float r0d, r1d, r2d, r3d;  int r0j, r1j, r2j, r3j;
    #define EXTRACT_MIN(RD, RJ)                                        \
    {                                                                  \
        float md = e0; int mj = j0;                                    \
        for (int off = 32; off > 0; off >>= 1) {                       \
            float od = __shfl_xor(md, off, 64);                        \
            int   oj = __shfl_xor(mj, off, 64);                        \
            bool keep = dless(md, mj, od, oj);                         \
            md = keep ? md : od;                                       \
            mj = keep ? mj : oj;                                       \
        }                                                              \
        RD = md; RJ = mj;                                              \
        bool pop = (j0 == mj);                                         \
        e0 = pop ? e1 : e0;  j0 = pop ? j1 : j0;                       \
        e1 = pop ? e2 : e1;  j1 = pop ? j2 : j1;                       \
        e2 = pop ? e3 : e2;  j2 = pop ? j3 : j2;                       \
        e3 = pop ? 1e12f : e3;  j3 = pop ? INT_MAX : j3;               \
    }
    EXTRACT_MIN(r0d, r0j)
    EXTRACT_MIN(r1d, r1j)
    EXTRACT_MIN(r2d, r2j)
    EXTRACT_MIN(r3d, r3j)
    #undef EXTRACT_MIN

    if (lane == 0) {
        float qiv = 0.0f, vf = 0.0f;
        float dd0 = sqrtf(r0d), dd1 = sqrtf(r1d), dd2 = sqrtf(r2d), dd3 = sqrtf(r3d);
        if (dd3 < CUTOFF_F) {
            float ux[4], uy[4], uz[4];
            float dd[4]  = {dd0, dd1, dd2, dd3};
            int   jj4[4] = {r0j, r1j, r2j, r3j};
            #pragma unroll
            for (int k = 0; k < 4; ++k) {
                const float4 pj = p4[jj4[k]];
                float ex, ey, ez;
                if (diag) min_image<true >(K, xi - pj.x, yi - pj.y, zi - pj.z, ex, ey, ez);
                else      min_image<false>(K, xi - pj.x, yi - pj.y, zi - pj.z, ex, ey, ez);
                ux[k] = ex / dd[k];
                uy[k] = ey / dd[k];
                uz[k] = ez / dd[k];
            }
            float s2 = 0.0f;
            #pragma unroll
            for (int k = 0; k < 4; ++k)
                #pragma unroll
                for (int l = k + 1; l < 4; ++l) {
                    float cs = ux[k]*ux[l] + uy[k]*uy[l] + uz[k]*uz[l];
                    float t  = cs + (1.0f / 3.0f);
                    s2 += t * t;
                }
            qiv = 1.0f - 0.375f * s2;
            vf  = 1.0f;
        }
        qv[2*s]     = qiv;   // plain stores, zero contention
        qv[2*s + 1] = vf;
    }
}

// ---------------------------------------------------------------------------
__global__ __launch_bounds__(256) void k_finalize(const float* __restrict__ ws,
                                                  const float* __restrict__ rbins,
                                                  const float* __restrict__ qbins,
                                                  float* __restrict__ out,
                                                  int N, int nbins, int nq) {
    __shared__ float G[512];
    __shared__ float rq[256], rv[256];
    const int tid = threadIdx.x;
    const float rho = ws[10];
    const float dr  = rbins[1] - rbins[0];
    const float FOURPI = 4.0f * 3.14159265358979323846f;

    for (int t = tid; t < nbins; t += blockDim.x) {
        float h = 0.0f;
        for (int c = 0; c < NCOPIES; ++c) h += ws[WS_HIST + c * nbins + t];
        float r = rbins[t];
        float shell = FOURPI * r * r * dr;
        float g = h / ((float)N * rho * shell);
        G[t] = g;
        if (blockIdx.x == 0) {
            out[t] = g;
            out[nbins + t] = FOURPI * rho * r * g;
        }
    }

    // block 0: reduce per-Si (qi*vf, vf) slots
    if (blockIdx.x == 0) {
        const int nsi = ((const int*)ws)[14];
        const float* qv = ws + WS_POS4 + 12 * (size_t)N;
        float sq = 0.0f, sv = 0.0f;
        for (int s = tid; s < nsi; s += 256) {
            sq += qv[2*s];
            sv += qv[2*s + 1];
        }
        rq[tid] = sq; rv[tid] = sv;
    }
    __syncthreads();
    if (blockIdx.x == 0) {
        for (int s = 128; s > 0; s >>= 1) {
            if (tid < s) { rq[tid] += rq[tid + s]; rv[tid] += rv[tid + s]; }
            __syncthreads();
        }
        if (tid == 0)
            out[2 * nbins + nq] = rq[0] / fmaxf(rv[0], 1.0f);
    }

    int q = blockIdx.x * blockDim.x + tid;
    if (q < nq) {
        float qq = qbins[q];
        float s = 0.0f;
        for (int t = 0; t < nbins; ++t) {
            float r  = rbins[t];
            float qr = qq * r;
            float sc = sinf(qr) / qr;          // jnp.sinc(qr/pi)
            s += r * r * (G[t] - 1.0f) * sc;
        }
        out[2 * nbins + q] = 1.0f + FOURPI * rho * dr * s;
    }
}

// ---------------------------------------------------------------------------
extern "C" void kernel_launch(void* const* d_in, const int* in_sizes, int n_in,
                              void* d_out, int out_size, void* d_ws, size_t ws_size,
                              hipStream_t stream) {
    const float* pos     = (const float*)d_in[0];
    const float* cell    = (const float*)d_in[1];
    const float* rbins   = (const float*)d_in[2];
    const float* qbins   = (const float*)d_in[3];
    const int*   species = (const int*)d_in[4];
    float* out = (float*)d_out;
    float* ws  = (float*)d_ws;

    const int N     = in_sizes[4];
    const int nbins = in_sizes[2];
    const int nq    = in_sizes[3];

    const int T = (N + 127) / 128;          // 128-atom tiles
    const int P = T * (T + 1) / 2;          // upper-tri tile pairs

    k_init<<<17, 256, 0, stream>>>(cell, pos, species, ws, N, nbins);
    k_hist<<<2 * P, 256, 0, stream>>>(cell, rbins, ws, N, nbins, T);
    k_top4<<<N, 64, 0, stream>>>(cell, ws, N);
    k_finalize<<<(nq + 255) / 256, 256, 0, stream>>>(ws, rbins, qbins, out, N, nbins, nq);
}

// Round 6
// 120.693 us; speedup vs baseline: 1.5089x; 1.2659x over previous
//
#include <hip/hip_runtime.h>
#include <climits>
#include <math.h>

// ---------------------------------------------------------------------------
// DescriptorModel: neutron-weighted G(r), T(r), S(Q), tetrahedral q over Si.
// R6: k_finalize's S(Q) loop de-serialized. R5 evidence: k_finalize 43.5us =
// ~520 cyc/iter for 200 iters — OCML sinf's branches blocked load pipelining;
// each iter paid L2 + LDS latency + sinf serially. Now: integrand staged as
// float2 in LDS, branch-free v_sin_f32 (revolutions) + v_rcp, 4x unroll with
// 4 accumulators. k_hist/k_top4/k_init unchanged (R5 fixed k_top4 spill).
// ---------------------------------------------------------------------------

#define B_SI_F 4.1491f
#define B_O_F  5.803f
#define CUTOFF_F 3.5f
#define NCOPIES 16

// ws float layout:
//  [0..8]  inv(cell)   [9] w_scale   [10] rho   [11] diag flag
//  [14] n_si (int)  [15] n_o (int)
//  [16 .. 16+NCOPIES*nbins)  histogram copies
//  [WS_POS4 ..]  p4[N] float4 ; si4[N] ; o4[N] ; qv[2N] (per-Si qi*vf, vf)
#define WS_HIST 16
#define WS_POS4 4096   // requires 16 + NCOPIES*nbins <= 4096

__device__ __forceinline__ bool dless(float da, int ia, float db, int ib) {
    return (da < db) || (da == db && ia < ib);
}

struct CellK {
    float ci0, ci1, ci2, ci3, ci4, ci5, ci6, ci7, ci8;
    float c0, c1, c2, c3, c4, c5, c6, c7, c8;
};

__device__ __forceinline__ CellK load_cell(const float* __restrict__ ws,
                                           const float* __restrict__ cellm) {
    CellK K;
    K.ci0 = ws[0]; K.ci1 = ws[1]; K.ci2 = ws[2];
    K.ci3 = ws[3]; K.ci4 = ws[4]; K.ci5 = ws[5];
    K.ci6 = ws[6]; K.ci7 = ws[7]; K.ci8 = ws[8];
    K.c0 = cellm[0]; K.c1 = cellm[1]; K.c2 = cellm[2];
    K.c3 = cellm[3]; K.c4 = cellm[4]; K.c5 = cellm[5];
    K.c6 = cellm[6]; K.c7 = cellm[7]; K.c8 = cellm[8];
    return K;
}

template<bool DIAG>
__device__ __forceinline__ void min_image(const CellK& K,
                                          float dx, float dy, float dz,
                                          float& ex, float& ey, float& ez) {
    if (DIAG) {
        float t0 = dx * K.ci0, t1 = dy * K.ci4, t2 = dz * K.ci8;
        t0 -= rintf(t0);  t1 -= rintf(t1);  t2 -= rintf(t2);
        ex = t0 * K.c0;  ey = t1 * K.c4;  ez = t2 * K.c8;
    } else {
        float f0 = dx*K.ci0 + dy*K.ci3 + dz*K.ci6;
        float f1 = dx*K.ci1 + dy*K.ci4 + dz*K.ci7;
        float f2 = dx*K.ci2 + dy*K.ci5 + dz*K.ci8;
        f0 -= rintf(f0);  f1 -= rintf(f1);  f2 -= rintf(f2);
        ex = f0*K.c0 + f1*K.c3 + f2*K.c6;
        ey = f0*K.c1 + f1*K.c4 + f2*K.c7;
        ez = f0*K.c2 + f1*K.c5 + f2*K.c8;
    }
}

// ---------------------------------------------------------------------------
__global__ __launch_bounds__(256) void k_init(const float* __restrict__ cell,
                                              const float* __restrict__ pos,
                                              const int* __restrict__ species,
                                              float* __restrict__ ws, int N, int nbins) {
    const int tid = threadIdx.x;
    float4* p4  = (float4*)(ws + WS_POS4);
    float4* si4 = p4 + N;
    float4* o4  = si4 + N;

    if (blockIdx.x != 0) {
        const int nb = (int)gridDim.x - 1;      // 16
        const int cid = (int)blockIdx.x - 1;
        const int tot = NCOPIES * nbins;
        for (int i = cid * 256 + tid; i < tot; i += nb * 256)
            ws[WS_HIST + i] = 0.0f;
        for (int j = cid * 256 + tid; j < N; j += nb * 256) {
            float b = (species[j] == 0) ? B_SI_F : B_O_F;
            p4[j] = make_float4(pos[3*j], pos[3*j+1], pos[3*j+2], b);
        }
        return;
    }

    // ---- block 0: ordered compaction of Si / O lists ----
    const int per = (N + 255) / 256;
    const int lo = tid * per, hi = min(N, lo + per);
    int csi = 0, co = 0;
    for (int j = lo; j < hi; ++j) {
        if (species[j] == 0) csi++; else co++;
    }
    __shared__ int psi[256], po[256];
    psi[tid] = csi; po[tid] = co;
    __syncthreads();
    for (int off = 1; off < 256; off <<= 1) {
        int a = (tid >= off) ? psi[tid - off] : 0;
        int b = (tid >= off) ? po[tid - off]  : 0;
        __syncthreads();
        psi[tid] += a; po[tid] += b;
        __syncthreads();
    }
    int wsi = psi[tid] - csi, wo = po[tid] - co;
    for (int j = lo; j < hi; ++j) {
        float x = pos[3*j], y = pos[3*j+1], z = pos[3*j+2];
        if (species[j] == 0) si4[wsi++] = make_float4(x, y, z, __int_as_float(j));
        else                 o4[wo++]   = make_float4(x, y, z, __int_as_float(j));
    }

    if (tid == 0) {
        int nSi = psi[255];
        ((int*)ws)[14] = nSi;
        ((int*)ws)[15] = po[255];
        double m[9];
        #pragma unroll
        for (int i = 0; i < 9; ++i) m[i] = (double)cell[i];
        double det = m[0]*(m[4]*m[8]-m[5]*m[7])
                   - m[1]*(m[3]*m[8]-m[5]*m[6])
                   + m[2]*(m[3]*m[7]-m[4]*m[6]);
        double inv[9];
        inv[0] =  (m[4]*m[8]-m[5]*m[7])/det;
        inv[1] = -(m[1]*m[8]-m[2]*m[7])/det;
        inv[2] =  (m[1]*m[5]-m[2]*m[4])/det;
        inv[3] = -(m[3]*m[8]-m[5]*m[6])/det;
        inv[4] =  (m[0]*m[8]-m[2]*m[6])/det;
        inv[5] = -(m[0]*m[5]-m[2]*m[3])/det;
        inv[6] =  (m[3]*m[7]-m[4]*m[6])/det;
        inv[7] = -(m[0]*m[7]-m[1]*m[6])/det;
        inv[8] =  (m[0]*m[4]-m[1]*m[3])/det;
        #pragma unroll
        for (int i = 0; i < 9; ++i) ws[i] = (float)inv[i];
        float mean_b = ((float)nSi * B_SI_F + (float)(N - nSi) * B_O_F) / (float)N;
        ws[9]  = 1.0f / (mean_b * mean_b);
        ws[10] = (float)N / (float)fabs(det);
        bool diag = (cell[1] == 0.0f) && (cell[2] == 0.0f) && (cell[3] == 0.0f) &&
                    (cell[5] == 0.0f) && (cell[6] == 0.0f) && (cell[7] == 0.0f);
        ws[11] = diag ? 1.0f : 0.0f;
    }
}

// ---------------------------------------------------------------------------
// k_hist: symmetry-halved pair histogram over 128x128 tile pairs.
template<bool DIAG>
__device__ __forceinline__ void hist_sweep(const CellK& K, const float4* __restrict__ p4,
                                           int jbase, int jend,
                                           float xi, float yi, float zi, float wi,
                                           float rb0, float inv_dr, int nbins_m1,
                                           float* shist) {
    #pragma unroll 4
    for (int j = jbase; j < jend; ++j) {
        int ju = __builtin_amdgcn_readfirstlane(j);   // wave-uniform -> s_load
        const float4 pj = p4[ju];
        float ex, ey, ez;
        min_image<DIAG>(K, xi - pj.x, yi - pj.y, zi - pj.z, ex, ey, ez);
        float dist = __builtin_amdgcn_sqrtf(fmaf(ex, ex, fmaf(ey, ey, ez * ez)));
        float x  = (dist - rb0) * inv_dr;
        float fl = floorf(x);
        int   i0 = (int)fl;
        if (i0 >= 0 && i0 < nbins_m1) {
            float w = wi * pj.w;
            float f = x - fl;
            atomicAdd(&shist[i0],     w * (1.0f - f));
            atomicAdd(&shist[i0 + 1], w * f);
        }
    }
}

__global__ __launch_bounds__(256) void k_hist(const float* __restrict__ cellm,
                                              const float* __restrict__ rbins,
                                              float* __restrict__ ws,
                                              int N, int nbins, int T) {
    const int tid = threadIdx.x;
    const int bid = blockIdx.x;
    const int jhalf = bid & 1;
    int rem = bid >> 1;
    int ti = 0;
    while (rem >= T - ti) { rem -= T - ti; ti++; }
    const int tj = ti + rem;

    __shared__ float shist[256];
    for (int t = tid; t < 256; t += 256) shist[t] = 0.0f;

    const CellK K = load_cell(ws, cellm);
    const float w_scale = ws[9];
    const bool  diag    = (ws[11] != 0.0f);
    const float rb0     = rbins[0];
    const float inv_dr  = 1.0f / (rbins[1] - rbins[0]);
    const int   nbins_m1 = nbins - 1;

    const float4* __restrict__ p4 = (const float4*)(ws + WS_POS4);
    const int il  = tid & 127;
    const int sub = tid >> 7;
    const int i   = ti * 128 + il;
    const float4 pi_ = p4[min(i, N - 1)];
    const float xi = pi_.x, yi = pi_.y, zi = pi_.z;
    const float wmul = (ti == tj) ? 1.0f : 2.0f;
    const float wi = (i < N) ? pi_.w * w_scale * wmul : 0.0f;

    const int jbase = tj * 128 + jhalf * 64 + sub * 32;
    const int jend  = min(jbase + 32, N);

    __syncthreads();

    if (diag) hist_sweep<true >(K, p4, jbase, jend, xi, yi, zi, wi, rb0, inv_dr, nbins_m1, shist);
    else      hist_sweep<false>(K, p4, jbase, jend, xi, yi, zi, wi, rb0, inv_dr, nbins_m1, shist);

    __syncthreads();

    float* gh = ws + WS_HIST + (size_t)(bid % NCOPIES) * nbins;
    for (int t = tid; t < nbins; t += 256) {
        float h = shist[t];
        if (h != 0.0f) atomicAdd(&gh[t], h);
    }
}

// ---------------------------------------------------------------------------
// k_top4: one wave per Si atom; named-scalar top-4, nothing spillable.
template<bool DIAG>
__device__ __forceinline__ void top4_sweep_s(const CellK& K, const float4* __restrict__ o4,
                                             int no, int lane,
                                             float xi, float yi, float zi,
                                             float& e0, float& e1, float& e2, float& e3,
                                             int& j0, int& j1, int& j2, int& j3) {
    for (int k = lane; k < no; k += 64) {
        const float4 o = o4[k];
        float ex, ey, ez;
        min_image<DIAG>(K, xi - o.x, yi - o.y, zi - o.z, ex, ey, ez);
        float c  = fmaf(ex, ex, fmaf(ey, ey, ez * ez));
        int   jc = __float_as_int(o.w);
        if (dless(c, jc, e3, j3)) {            // rare; exec-mask skip otherwise
            bool lt2 = dless(c, jc, e2, j2);
            bool lt1 = dless(c, jc, e1, j1);
            bool lt0 = dless(c, jc, e0, j0);
            e3 = lt2 ? e2 : c;               j3 = lt2 ? j2 : jc;
            e2 = lt2 ? (lt1 ? e1 : c) : e2;  j2 = lt2 ? (lt1 ? j1 : jc) : j2;
            e1 = lt1 ? (lt0 ? e0 : c) : e1;  j1 = lt1 ? (lt0 ? j0 : jc) : j1;
            e0 = lt0 ? c : e0;               j0 = lt0 ? jc : j0;
        }
    }
}

__global__ __launch_bounds__(64) void k_top4(const float* __restrict__ cellm,
                                             float* __restrict__ ws, int N) {
    const int nsi = ((const int*)ws)[14];
    const int s = blockIdx.x;
    if (s >= nsi) return;
    const int no = ((const int*)ws)[15];
    const int lane = threadIdx.x;

    const CellK K = load_cell(ws, cellm);
    const bool diag = (ws[11] != 0.0f);

    const float4* __restrict__ p4  = (const float4*)(ws + WS_POS4);
    const float4* __restrict__ si4 = p4 + N;
    const float4* __restrict__ o4  = si4 + N;
    float* __restrict__ qv = ws + WS_POS4 + 12 * (size_t)N;   // [2N]

    const float4 sc = si4[s];
    const float xi = sc.x, yi = sc.y, zi = sc.z;

    float e0 = 1e12f, e1 = 1e12f, e2 = 1e12f, e3 = 1e12f;
    int   j0 = INT_MAX, j1 = INT_MAX, j2 = INT_MAX, j3 = INT_MAX;

    if (diag) top4_sweep_s<true >(K, o4, no, lane, xi, yi, zi, e0, e1, e2, e3, j0, j1, j2, j3);
    else      top4_sweep_s<false>(K, o4, no, lane, xi, yi, zi, e0, e1, e2, e3, j0, j1, j2, j3);

    // wave merge: extract global min 4x (scalar state only).
    float r0d, r1d, r2d, r3d;  int r0j, r1j, r2j, r3j;
    #define EXTRACT_MIN(RD, RJ)                                        \
    {                                                                  \
        float md = e0; int mj = j0;                                    \
        for (int off = 32; off > 0; off >>= 1) {                       \
            float od = __shfl_xor(md, off, 64);                        \
            int   oj = __shfl_xor(mj, off, 64);                        \
            bool keep = dless(md, mj, od, oj);                         \
            md = keep ? md : od;                                       \
            mj = keep ? mj : oj;                                       \
        }                                                              \
        RD = md; RJ = mj;                                              \
        bool pop = (j0 == mj);                                         \
        e0 = pop ? e1 : e0;  j0 = pop ? j1 : j0;                       \
        e1 = pop ? e2 : e1;  j1 = pop ? j2 : j1;                       \
        e2 = pop ? e3 : e2;  j2 = pop ? j3 : j2;                       \
        e3 = pop ? 1e12f : e3;  j3 = pop ? INT_MAX : j3;               \
    }
    EXTRACT_MIN(r0d, r0j)
    EXTRACT_MIN(r1d, r1j)
    EXTRACT_MIN(r2d, r2j)
    EXTRACT_MIN(r3d, r3j)
    #undef EXTRACT_MIN

    if (lane == 0) {
        float qiv = 0.0f, vf = 0.0f;
        float dd0 = sqrtf(r0d), dd1 = sqrtf(r1d), dd2 = sqrtf(r2d), dd3 = sqrtf(r3d);
        if (dd3 < CUTOFF_F) {
            float ux[4], uy[4], uz[4];
            float dd[4]  = {dd0, dd1, dd2, dd3};
            int   jj4[4] = {r0j, r1j, r2j, r3j};
            #pragma unroll
            for (int k = 0; k < 4; ++k) {
                const float4 pj = p4[jj4[k]];
                float ex, ey, ez;
                if (diag) min_image<true >(K, xi - pj.x, yi - pj.y, zi - pj.z, ex, ey, ez);
                else      min_image<false>(K, xi - pj.x, yi - pj.y, zi - pj.z, ex, ey, ez);
                ux[k] = ex / dd[k];
                uy[k] = ey / dd[k];
                uz[k] = ez / dd[k];
            }
            float s2 = 0.0f;
            #pragma unroll
            for (int k = 0; k < 4; ++k)
                #pragma unroll
                for (int l = k + 1; l < 4; ++l) {
                    float cs = ux[k]*ux[l] + uy[k]*uy[l] + uz[k]*uz[l];
                    float t  = cs + (1.0f / 3.0f);
                    s2 += t * t;
                }
            qiv = 1.0f - 0.375f * s2;
            vf  = 1.0f;
        }
        qv[2*s]     = qiv;   // plain stores, zero contention
        qv[2*s + 1] = vf;
    }
}

// ---------------------------------------------------------------------------
// fast sin(x)/x via v_sin_f32 (input in revolutions, rintf reduction) and
// v_rcp_f32. Branch-free: lets the compiler pipeline LDS loads across iters.
__device__ __forceinline__ float fast_sinc(float x) {
    float rev = x * 0.15915494309189535f;     // x / (2*pi)
    rev -= rintf(rev);                        // [-0.5, 0.5] revolutions
    float sn = __builtin_amdgcn_sinf(rev);    // sin(2*pi*rev) = sin(x)
    return sn * __builtin_amdgcn_rcpf(x);
}

__global__ __launch_bounds__(256) void k_finalize(const float* __restrict__ ws,
                                                  const float* __restrict__ rbins,
                                                  const float* __restrict__ qbins,
                                                  float* __restrict__ out,
                                                  int N, int nbins, int nq) {
    __shared__ float2 srw[256];               // (r, r^2*(G-1)) per bin
    __shared__ float rq[256], rv[256];
    const int tid = threadIdx.x;
    const float rho = ws[10];
    const float dr  = rbins[1] - rbins[0];
    const float FOURPI = 4.0f * 3.14159265358979323846f;

    for (int t = tid; t < nbins; t += blockDim.x) {
        float h = 0.0f;
        #pragma unroll
        for (int c = 0; c < NCOPIES; ++c) h += ws[WS_HIST + c * nbins + t];
        float r = rbins[t];
        float shell = FOURPI * r * r * dr;
        float g = h / ((float)N * rho * shell);
        srw[t] = make_float2(r, r * r * (g - 1.0f));
        if (blockIdx.x == 0) {
            out[t] = g;
            out[nbins + t] = FOURPI * rho * r * g;
        }
    }

    // block 0: reduce per-Si (qi*vf, vf) slots
    if (blockIdx.x == 0) {
        const int nsi = ((const int*)ws)[14];
        const float* qv = ws + WS_POS4 + 12 * (size_t)N;
        float sq = 0.0f, sv = 0.0f;
        for (int s = tid; s < nsi; s += 256) {
            sq += qv[2*s];
            sv += qv[2*s + 1];
        }
        rq[tid] = sq; rv[tid] = sv;
    }
    __syncthreads();
    if (blockIdx.x == 0) {
        for (int s = 128; s > 0; s >>= 1) {
            if (tid < s) { rq[tid] += rq[tid + s]; rv[tid] += rv[tid + s]; }
            __syncthreads();
        }
        if (tid == 0)
            out[2 * nbins + nq] = rq[0] / fmaxf(rv[0], 1.0f);
    }

    int q = blockIdx.x * blockDim.x + tid;
    if (q < nq) {
        float qq = qbins[q];
        float s0 = 0.0f, s1 = 0.0f, s2 = 0.0f, s3 = 0.0f;
        int t = 0;
        for (; t + 4 <= nbins; t += 4) {
            float2 a = srw[t], b = srw[t+1], c = srw[t+2], d = srw[t+3];
            s0 += a.y * fast_sinc(qq * a.x);
            s1 += b.y * fast_sinc(qq * b.x);
            s2 += c.y * fast_sinc(qq * c.x);
            s3 += d.y * fast_sinc(qq * d.x);
        }
        for (; t < nbins; ++t) {
            float2 a = srw[t];
            s0 += a.y * fast_sinc(qq * a.x);
        }
        float s = (s0 + s1) + (s2 + s3);
        out[2 * nbins + q] = 1.0f + FOURPI * rho * dr * s;
    }
}

// ---------------------------------------------------------------------------
extern "C" void kernel_launch(void* const* d_in, const int* in_sizes, int n_in,
                              void* d_out, int out_size, void* d_ws, size_t ws_size,
                              hipStream_t stream) {
    const float* pos     = (const float*)d_in[0];
    const float* cell    = (const float*)d_in[1];
    const float* rbins   = (const float*)d_in[2];
    const float* qbins   = (const float*)d_in[3];
    const int*   species = (const int*)d_in[4];
    float* out = (float*)d_out;
    float* ws  = (float*)d_ws;

    const int N     = in_sizes[4];
    const int nbins = in_sizes[2];
    const int nq    = in_sizes[3];

    const int T = (N + 127) / 128;          // 128-atom tiles
    const int P = T * (T + 1) / 2;          // upper-tri tile pairs

    k_init<<<17, 256, 0, stream>>>(cell, pos, species, ws, N, nbins);
    k_hist<<<2 * P, 256, 0, stream>>>(cell, rbins, ws, N, nbins, T);
    k_top4<<<N, 64, 0, stream>>>(cell, ws, N);
    k_finalize<<<(nq + 255) / 256, 256, 0, stream>>>(ws, rbins, qbins, out, N, nbins, nq);
}

// Round 7
// 109.684 us; speedup vs baseline: 1.6603x; 1.1004x over previous
//
#include <hip/hip_runtime.h>
#include <climits>
#include <math.h>

// ---------------------------------------------------------------------------
// DescriptorModel: neutron-weighted G(r), T(r), S(Q), tetrahedral q over Si.
// R7: merge k_top4 into k_hist's dispatch (k_top4 only depends on k_init, so
// its blocks now run CONCURRENTLY with hist blocks instead of serially after
// them; one fewer graph node). 3 dispatches total. R6 evidence: top-5 is all
// harness fillBuffer (268MB ws re-poison @ 85% HBM peak, 39.5us) — our
// kernels are each <39us; only serial structure left to claw back.
// ---------------------------------------------------------------------------

#define B_SI_F 4.1491f
#define B_O_F  5.803f
#define CUTOFF_F 3.5f
#define NCOPIES 16

// ws float layout:
//  [0..8]  inv(cell)   [9] w_scale   [10] rho   [11] diag flag
//  [14] n_si (int)  [15] n_o (int)
//  [16 .. 16+NCOPIES*nbins)  histogram copies
//  [WS_POS4 ..]  p4[N] float4 ; si4[N] ; o4[N] ; qv[2N] (per-Si qi*vf, vf)
#define WS_HIST 16
#define WS_POS4 4096   // requires 16 + NCOPIES*nbins <= 4096

__device__ __forceinline__ bool dless(float da, int ia, float db, int ib) {
    return (da < db) || (da == db && ia < ib);
}

struct CellK {
    float ci0, ci1, ci2, ci3, ci4, ci5, ci6, ci7, ci8;
    float c0, c1, c2, c3, c4, c5, c6, c7, c8;
};

__device__ __forceinline__ CellK load_cell(const float* __restrict__ ws,
                                           const float* __restrict__ cellm) {
    CellK K;
    K.ci0 = ws[0]; K.ci1 = ws[1]; K.ci2 = ws[2];
    K.ci3 = ws[3]; K.ci4 = ws[4]; K.ci5 = ws[5];
    K.ci6 = ws[6]; K.ci7 = ws[7]; K.ci8 = ws[8];
    K.c0 = cellm[0]; K.c1 = cellm[1]; K.c2 = cellm[2];
    K.c3 = cellm[3]; K.c4 = cellm[4]; K.c5 = cellm[5];
    K.c6 = cellm[6]; K.c7 = cellm[7]; K.c8 = cellm[8];
    return K;
}

template<bool DIAG>
__device__ __forceinline__ void min_image(const CellK& K,
                                          float dx, float dy, float dz,
                                          float& ex, float& ey, float& ez) {
    if (DIAG) {
        float t0 = dx * K.ci0, t1 = dy * K.ci4, t2 = dz * K.ci8;
        t0 -= rintf(t0);  t1 -= rintf(t1);  t2 -= rintf(t2);
        ex = t0 * K.c0;  ey = t1 * K.c4;  ez = t2 * K.c8;
    } else {
        float f0 = dx*K.ci0 + dy*K.ci3 + dz*K.ci6;
        float f1 = dx*K.ci1 + dy*K.ci4 + dz*K.ci7;
        float f2 = dx*K.ci2 + dy*K.ci5 + dz*K.ci8;
        f0 -= rintf(f0);  f1 -= rintf(f1);  f2 -= rintf(f2);
        ex = f0*K.c0 + f1*K.c3 + f2*K.c6;
        ey = f0*K.c1 + f1*K.c4 + f2*K.c7;
        ez = f0*K.c2 + f1*K.c5 + f2*K.c8;
    }
}

// ---------------------------------------------------------------------------
__global__ __launch_bounds__(256) void k_init(const float* __restrict__ cell,
                                              const float* __restrict__ pos,
                                              const int* __restrict__ species,
                                              float* __restrict__ ws, int N, int nbins) {
    const int tid = threadIdx.x;
    float4* p4  = (float4*)(ws + WS_POS4);
    float4* si4 = p4 + N;
    float4* o4  = si4 + N;

    if (blockIdx.x != 0) {
        const int nb = (int)gridDim.x - 1;      // 16
        const int cid = (int)blockIdx.x - 1;
        const int tot = NCOPIES * nbins;
        for (int i = cid * 256 + tid; i < tot; i += nb * 256)
            ws[WS_HIST + i] = 0.0f;
        for (int j = cid * 256 + tid; j < N; j += nb * 256) {
            float b = (species[j] == 0) ? B_SI_F : B_O_F;
            p4[j] = make_float4(pos[3*j], pos[3*j+1], pos[3*j+2], b);
        }
        return;
    }

    // ---- block 0: ordered compaction of Si / O lists ----
    const int per = (N + 255) / 256;
    const int lo = tid * per, hi = min(N, lo + per);
    int csi = 0, co = 0;
    for (int j = lo; j < hi; ++j) {
        if (species[j] == 0) csi++; else co++;
    }
    __shared__ int psi[256], po[256];
    psi[tid] = csi; po[tid] = co;
    __syncthreads();
    for (int off = 1; off < 256; off <<= 1) {
        int a = (tid >= off) ? psi[tid - off] : 0;
        int b = (tid >= off) ? po[tid - off]  : 0;
        __syncthreads();
        psi[tid] += a; po[tid] += b;
        __syncthreads();
    }
    int wsi = psi[tid] - csi, wo = po[tid] - co;
    for (int j = lo; j < hi; ++j) {
        float x = pos[3*j], y = pos[3*j+1], z = pos[3*j+2];
        if (species[j] == 0) si4[wsi++] = make_float4(x, y, z, __int_as_float(j));
        else                 o4[wo++]   = make_float4(x, y, z, __int_as_float(j));
    }

    if (tid == 0) {
        int nSi = psi[255];
        ((int*)ws)[14] = nSi;
        ((int*)ws)[15] = po[255];
        double m[9];
        #pragma unroll
        for (int i = 0; i < 9; ++i) m[i] = (double)cell[i];
        double det = m[0]*(m[4]*m[8]-m[5]*m[7])
                   - m[1]*(m[3]*m[8]-m[5]*m[6])
                   + m[2]*(m[3]*m[7]-m[4]*m[6]);
        double inv[9];
        inv[0] =  (m[4]*m[8]-m[5]*m[7])/det;
        inv[1] = -(m[1]*m[8]-m[2]*m[7])/det;
        inv[2] =  (m[1]*m[5]-m[2]*m[4])/det;
        inv[3] = -(m[3]*m[8]-m[5]*m[6])/det;
        inv[4] =  (m[0]*m[8]-m[2]*m[6])/det;
        inv[5] = -(m[0]*m[5]-m[2]*m[3])/det;
        inv[6] =  (m[3]*m[7]-m[4]*m[6])/det;
        inv[7] = -(m[0]*m[7]-m[1]*m[6])/det;
        inv[8] =  (m[0]*m[4]-m[1]*m[3])/det;
        #pragma unroll
        for (int i = 0; i < 9; ++i) ws[i] = (float)inv[i];
        float mean_b = ((float)nSi * B_SI_F + (float)(N - nSi) * B_O_F) / (float)N;
        ws[9]  = 1.0f / (mean_b * mean_b);
        ws[10] = (float)N / (float)fabs(det);
        bool diag = (cell[1] == 0.0f) && (cell[2] == 0.0f) && (cell[3] == 0.0f) &&
                    (cell[5] == 0.0f) && (cell[6] == 0.0f) && (cell[7] == 0.0f);
        ws[11] = diag ? 1.0f : 0.0f;
    }
}

// ---------------------------------------------------------------------------
// hist sweep body (blocks [0, P2) of k_main)
template<bool DIAG>
__device__ __forceinline__ void hist_sweep(const CellK& K, const float4* __restrict__ p4,
                                           int jbase, int jend,
                                           float xi, float yi, float zi, float wi,
                                           float rb0, float inv_dr, int nbins_m1,
                                           float* shist) {
    #pragma unroll 4
    for (int j = jbase; j < jend; ++j) {
        int ju = __builtin_amdgcn_readfirstlane(j);   // wave-uniform -> s_load
        const float4 pj = p4[ju];
        float ex, ey, ez;
        min_image<DIAG>(K, xi - pj.x, yi - pj.y, zi - pj.z, ex, ey, ez);
        float dist = __builtin_amdgcn_sqrtf(fmaf(ex, ex, fmaf(ey, ey, ez * ez)));
        float x  = (dist - rb0) * inv_dr;
        float fl = floorf(x);
        int   i0 = (int)fl;
        if (i0 >= 0 && i0 < nbins_m1) {
            float w = wi * pj.w;
            float f = x - fl;
            atomicAdd(&shist[i0],     w * (1.0f - f));
            atomicAdd(&shist[i0 + 1], w * f);
        }
    }
}

// top-4 sweep body (blocks >= P2 of k_main), named scalars only (no spill)
template<bool DIAG>
__device__ __forceinline__ void top4_sweep_s(const CellK& K, const float4* __restrict__ o4,
                                             int no, int lane,
                                             float xi, float yi, float zi,
                                             float& e0, float& e1, float& e2, float& e3,
                                             int& j0, int& j1, int& j2, int& j3) {
    for (int k = lane; k < no; k += 64) {
        const float4 o = o4[k];
        float ex, ey, ez;
        min_image<DIAG>(K, xi - o.x, yi - o.y, zi - o.z, ex, ey, ez);
        float c  = fmaf(ex, ex, fmaf(ey, ey, ez * ez));
        int   jc = __float_as_int(o.w);
        if (dless(c, jc, e3, j3)) {            // rare; exec-mask skip otherwise
            bool lt2 = dless(c, jc, e2, j2);
            bool lt1 = dless(c, jc, e1, j1);
            bool lt0 = dless(c, jc, e0, j0);
            e3 = lt2 ? e2 : c;               j3 = lt2 ? j2 : jc;
            e2 = lt2 ? (lt1 ? e1 : c) : e2;  j2 = lt2 ? (lt1 ? j1 : jc) : j2;
            e1 = lt1 ? (lt0 ? e0 : c) : e1;  j1 = lt1 ? (lt0 ? j0 : jc) : j1;
            e0 = lt0 ? c : e0;               j0 = lt0 ? jc : j0;
        }
    }
}

// ---------------------------------------------------------------------------
// k_main: blocks [0,P2) = symmetry-halved pair histogram (128x128 tile pairs,
// j wave-uniform). Blocks [P2, P2+ceil(N/4)) = top-4 Si kernel, one wave per
// Si atom (4 waves/block). Runs concurrently inside one dispatch.
__global__ __launch_bounds__(256) void k_main(const float* __restrict__ cellm,
                                              const float* __restrict__ rbins,
                                              float* __restrict__ ws,
                                              int N, int nbins, int T, int P2) {
    const int tid = threadIdx.x;
    const int bid = blockIdx.x;

    const CellK K = load_cell(ws, cellm);
    const bool diag = (ws[11] != 0.0f);
    const float4* __restrict__ p4 = (const float4*)(ws + WS_POS4);

    if (bid < P2) {
        // ---------------- histogram path ----------------
        const int jhalf = bid & 1;
        int rem = bid >> 1;
        int ti = 0;
        while (rem >= T - ti) { rem -= T - ti; ti++; }
        const int tj = ti + rem;

        __shared__ float shist[256];
        shist[tid] = 0.0f;

        const float w_scale = ws[9];
        const float rb0     = rbins[0];
        const float inv_dr  = 1.0f / (rbins[1] - rbins[0]);
        const int   nbins_m1 = nbins - 1;

        const int il  = tid & 127;
        const int sub = tid >> 7;
        const int i   = ti * 128 + il;
        const float4 pi_ = p4[min(i, N - 1)];
        const float xi = pi_.x, yi = pi_.y, zi = pi_.z;
        const float wmul = (ti == tj) ? 1.0f : 2.0f;
        const float wi = (i < N) ? pi_.w * w_scale * wmul : 0.0f;

        const int jbase = tj * 128 + jhalf * 64 + sub * 32;
        const int jend  = min(jbase + 32, N);

        __syncthreads();

        if (diag) hist_sweep<true >(K, p4, jbase, jend, xi, yi, zi, wi, rb0, inv_dr, nbins_m1, shist);
        else      hist_sweep<false>(K, p4, jbase, jend, xi, yi, zi, wi, rb0, inv_dr, nbins_m1, shist);

        __syncthreads();

        float* gh = ws + WS_HIST + (size_t)(bid % NCOPIES) * nbins;
        for (int t = tid; t < nbins; t += 256) {
            float h = shist[t];
            if (h != 0.0f) atomicAdd(&gh[t], h);
        }
        return;
    }

    // ---------------- top-4 path: one wave per Si atom ----------------
    const int nsi = ((const int*)ws)[14];
    const int s = (bid - P2) * 4 + (tid >> 6);
    if (s >= nsi) return;
    const int no = ((const int*)ws)[15];
    const int lane = tid & 63;

    const float4* __restrict__ si4 = p4 + N;
    const float4* __restrict__ o4  = si4 + N;
    float* __restrict__ qv = ws + WS_POS4 + 12 * (size_t)N;   // [2N]

    const float4 sc = si4[s];
    const float xi = sc.x, yi = sc.y, zi = sc.z;

    float e0 = 1e12f, e1 = 1e12f, e2 = 1e12f, e3 = 1e12f;
    int   j0 = INT_MAX, j1 = INT_MAX, j2 = INT_MAX, j3 = INT_MAX;

    if (diag) top4_sweep_s<true >(K, o4, no, lane, xi, yi, zi, e0, e1, e2, e3, j0, j1, j2, j3);
    else      top4_sweep_s<false>(K, o4, no, lane, xi, yi, zi, e0, e1, e2, e3, j0, j1, j2, j3);

    // wave merge: extract global min 4x (scalar state only).
    float r0d, r1d, r2d, r3d;  int r0j, r1j, r2j, r3j;
    #define EXTRACT_MIN(RD, RJ)                                        \
    {                                                                  \
        float md = e0; int mj = j0;                                    \
        for (int off = 32; off > 0; off >>= 1) {                       \
            float od = __shfl_xor(md, off, 64);                        \
            int   oj = __shfl_xor(mj, off, 64);                        \
            bool keep = dless(md, mj, od, oj);                         \
            md = keep ? md : od;                                       \
            mj = keep ? mj : oj;                                       \
        }                                                              \
        RD = md; RJ = mj;                                              \
        bool pop = (j0 == mj);                                         \
        e0 = pop ? e1 : e0;  j0 = pop ? j1 : j0;                       \
        e1 = pop ? e2 : e1;  j1 = pop ? j2 : j1;                       \
        e2 = pop ? e3 : e2;  j2 = pop ? j3 : j2;                       \
        e3 = pop ? 1e12f : e3;  j3 = pop ? INT_MAX : j3;               \
    }
    EXTRACT_MIN(r0d, r0j)
    EXTRACT_MIN(r1d, r1j)
    EXTRACT_MIN(r2d, r2j)
    EXTRACT_MIN(r3d, r3j)
    #undef EXTRACT_MIN

    if (lane == 0) {
        float qiv = 0.0f, vf = 0.0f;
        float dd0 = sqrtf(r0d), dd1 = sqrtf(r1d), dd2 = sqrtf(r2d), dd3 = sqrtf(r3d);
        if (dd3 < CUTOFF_F) {
            float ux[4], uy[4], uz[4];
            float dd[4]  = {dd0, dd1, dd2, dd3};
            int   jj4[4] = {r0j, r1j, r2j, r3j};
            #pragma unroll
            for (int k = 0; k < 4; ++k) {
                const float4 pj = p4[jj4[k]];
                float ex, ey, ez;
                if (diag) min_image<true >(K, xi - pj.x, yi - pj.y, zi - pj.z, ex, ey, ez);
                else      min_image<false>(K, xi - pj.x, yi - pj.y, zi - pj.z, ex, ey, ez);
                ux[k] = ex / dd[k];
                uy[k] = ey / dd[k];
                uz[k] = ez / dd[k];
            }
            float s2 = 0.0f;
            #pragma unroll
            for (int k = 0; k < 4; ++k)
                #pragma unroll
                for (int l = k + 1; l < 4; ++l) {
                    float cs = ux[k]*ux[l] + uy[k]*uy[l] + uz[k]*uz[l];
                    float t  = cs + (1.0f / 3.0f);
                    s2 += t * t;
                }
            qiv = 1.0f - 0.375f * s2;
            vf  = 1.0f;
        }
        qv[2*s]     = qiv;   // plain stores, zero contention
        qv[2*s + 1] = vf;
    }
}

// ---------------------------------------------------------------------------
// fast sin(x)/x via v_sin_f32 (input in revolutions, rintf reduction) and
// v_rcp_f32. Branch-free: lets the compiler pipeline LDS loads across iters.
__device__ __forceinline__ float fast_sinc(float x) {
    float rev = x * 0.15915494309189535f;     // x / (2*pi)
    rev -= rintf(rev);                        // [-0.5, 0.5] revolutions
    float sn = __builtin_amdgcn_sinf(rev);    // sin(2*pi*rev) = sin(x)
    return sn * __builtin_amdgcn_rcpf(x);
}

__global__ __launch_bounds__(256) void k_finalize(const float* __restrict__ ws,
                                                  const float* __restrict__ rbins,
                                                  const float* __restrict__ qbins,
                                                  float* __restrict__ out,
                                                  int N, int nbins, int nq) {
    __shared__ float2 srw[256];               // (r, r^2*(G-1)) per bin
    __shared__ float rq[256], rv[256];
    const int tid = threadIdx.x;
    const float rho = ws[10];
    const float dr  = rbins[1] - rbins[0];
    const float FOURPI = 4.0f * 3.14159265358979323846f;

    for (int t = tid; t < nbins; t += blockDim.x) {
        float h = 0.0f;
        #pragma unroll
        for (int c = 0; c < NCOPIES; ++c) h += ws[WS_HIST + c * nbins + t];
        float r = rbins[t];
        float shell = FOURPI * r * r * dr;
        float g = h / ((float)N * rho * shell);
        srw[t] = make_float2(r, r * r * (g - 1.0f));
        if (blockIdx.x == 0) {
            out[t] = g;
            out[nbins + t] = FOURPI * rho * r * g;
        }
    }

    // block 0: reduce per-Si (qi*vf, vf) slots
    if (blockIdx.x == 0) {
        const int nsi = ((const int*)ws)[14];
        const float* qv = ws + WS_POS4 + 12 * (size_t)N;
        float sq = 0.0f, sv = 0.0f;
        for (int s = tid; s < nsi; s += 256) {
            sq += qv[2*s];
            sv += qv[2*s + 1];
        }
        rq[tid] = sq; rv[tid] = sv;
    }
    __syncthreads();
    if (blockIdx.x == 0) {
        for (int s = 128; s > 0; s >>= 1) {
            if (tid < s) { rq[tid] += rq[tid + s]; rv[tid] += rv[tid + s]; }
            __syncthreads();
        }
        if (tid == 0)
            out[2 * nbins + nq] = rq[0] / fmaxf(rv[0], 1.0f);
    }

    int q = blockIdx.x * blockDim.x + tid;
    if (q < nq) {
        float qq = qbins[q];
        float s0 = 0.0f, s1 = 0.0f, s2 = 0.0f, s3 = 0.0f;
        int t = 0;
        for (; t + 4 <= nbins; t += 4) {
            float2 a = srw[t], b = srw[t+1], c = srw[t+2], d = srw[t+3];
            s0 += a.y * fast_sinc(qq * a.x);
            s1 += b.y * fast_sinc(qq * b.x);
            s2 += c.y * fast_sinc(qq * c.x);
            s3 += d.y * fast_sinc(qq * d.x);
        }
        for (; t < nbins; ++t) {
            float2 a = srw[t];
            s0 += a.y * fast_sinc(qq * a.x);
        }
        float s = (s0 + s1) + (s2 + s3);
        out[2 * nbins + q] = 1.0f + FOURPI * rho * dr * s;
    }
}

// ---------------------------------------------------------------------------
extern "C" void kernel_launch(void* const* d_in, const int* in_sizes, int n_in,
                              void* d_out, int out_size, void* d_ws, size_t ws_size,
                              hipStream_t stream) {
    const float* pos     = (const float*)d_in[0];
    const float* cell    = (const float*)d_in[1];
    const float* rbins   = (const float*)d_in[2];
    const float* qbins   = (const float*)d_in[3];
    const int*   species = (const int*)d_in[4];
    float* out = (float*)d_out;
    float* ws  = (float*)d_ws;

    const int N     = in_sizes[4];
    const int nbins = in_sizes[2];
    const int nq    = in_sizes[3];

    const int T  = (N + 127) / 128;         // 128-atom tiles
    const int P2 = T * (T + 1);             // 2 * upper-tri tile pairs
    const int BT = (N + 3) / 4;             // top-4 blocks (4 Si waves each)

    k_init<<<17, 256, 0, stream>>>(cell, pos, species, ws, N, nbins);
    k_main<<<P2 + BT, 256, 0, stream>>>(cell, rbins, ws, N, nbins, T, P2);
    k_finalize<<<(nq + 255) / 256, 256, 0, stream>>>(ws, rbins, qbins, out, N, nbins, nq);
}